// Round 4
// baseline (1886.844 us; speedup 1.0000x reference)
//
#include <hip/hip_runtime.h>
#include <math.h>

#define NEG 0.2f

__device__ __forceinline__ float leaky(float x){ return x >= 0.f ? x : NEG*x; }

// monotonic float<->uint key for atomicMax on floats (all-finite inputs)
__device__ __forceinline__ unsigned fkey(float x){
    unsigned u = __float_as_uint(x);
    return (u & 0x80000000u) ? ~u : (u | 0x80000000u);
}
__device__ __forceinline__ float funkey(unsigned k){
    unsigned u = (k & 0x80000000u) ? (k & 0x7FFFFFFFu) : ~k;
    return __uint_as_float(u);
}

// h1[n][c] = sum_i x[n][i] * W1[i][c]   (thread per output element)
__global__ void n_gemm1(const float* __restrict__ x, const float* __restrict__ W1,
                        float* __restrict__ h1, int N){
    int idx = blockIdx.x*256 + threadIdx.x;
    if (idx >= N*64) return;
    int n = idx >> 6, c = idx & 63;
    const float* xr = x + (size_t)n*128;
    float acc = 0.f;
    for (int i = 0; i < 128; ++i) acc = fmaf(xr[i], W1[i*64 + c], acc);
    h1[idx] = acc;
}

// s[n] = h[n]·a_s, d[n] = h[n]·a_d   (thread per node)
__global__ void n_sd(const float* __restrict__ h, const float* __restrict__ a_s,
                     const float* __restrict__ a_d, float* __restrict__ s,
                     float* __restrict__ d, int N, int C){
    int n = blockIdx.x*256 + threadIdx.x;
    if (n >= N) return;
    float sv = 0.f, dv = 0.f;
    for (int c = 0; c < C; ++c){
        float hv = h[(size_t)n*C + c];
        sv = fmaf(hv, a_s[c], sv);
        dv = fmaf(hv, a_d[c], dv);
    }
    s[n] = sv; d[n] = dv;
}

// e[i] = leaky(s[src]+d[dst]) stored in p; segment_max via atomicMax on keys.
// edges i<E from edge_index, i>=E are self-loops (src=dst=i-E).
__global__ void n_score(const int* __restrict__ ei, const float* __restrict__ s,
                        const float* __restrict__ d, float* __restrict__ p,
                        unsigned* __restrict__ mkey, int E, int ET){
    int i = blockIdx.x*256 + threadIdx.x;
    if (i >= ET) return;
    int src = (i < E) ? ei[i]     : (i - E);
    int dst = (i < E) ? ei[E + i] : (i - E);
    float ev = leaky(s[src] + d[dst]);
    p[i] = ev;
    atomicMax(&mkey[dst], fkey(ev));
}

// in-place p[i] = exp(e[i]-m[dst]); z[dst] += p[i]
__global__ void n_z(const int* __restrict__ ei, const unsigned* __restrict__ mkey,
                    float* __restrict__ p, float* __restrict__ z, int E, int ET){
    int i = blockIdx.x*256 + threadIdx.x;
    if (i >= ET) return;
    int dst = (i < E) ? ei[E + i] : (i - E);
    float pv = expf(p[i] - funkey(mkey[dst]));
    p[i] = pv;
    atomicAdd(&z[dst], pv);
}

// ---------------- CSR build over ALL ET edges (incl. self-loops), storing edge ids
__global__ void k_count(const int* __restrict__ ei, int* __restrict__ cnt, int E, int ET){
    int i = blockIdx.x*256 + threadIdx.x;
    if (i >= ET) return;
    int dst = (i < E) ? ei[E + i] : (i - E);
    atomicAdd(&cnt[dst], 1);
}
__global__ void k_scan1(const int* __restrict__ cnt, int* __restrict__ bsum, int n){
    __shared__ int sh[256];
    int b = blockIdx.x, tid = threadIdx.x;
    int start = b*1024, s = 0;
    for (int i = tid; i < 1024; i += 256){ int idx = start+i; s += (idx<n)?cnt[idx]:0; }
    sh[tid]=s; __syncthreads();
    for (int d=128; d>0; d>>=1){ if (tid<d) sh[tid]+=sh[tid+d]; __syncthreads(); }
    if (tid==0) bsum[b]=sh[0];
}
__global__ void k_scan2(int* bsum, int nb){
    if (threadIdx.x==0 && blockIdx.x==0){
        int run=0;
        for (int i=0;i<nb;i++){ int v=bsum[i]; bsum[i]=run; run+=v; }
    }
}
__global__ void k_scan3(const int* __restrict__ cnt, const int* __restrict__ bsum,
                        int* __restrict__ rowptr, int* __restrict__ wptr, int n){
    __shared__ int sh[256];
    int b = blockIdx.x, tid = threadIdx.x;
    int i0 = b*1024 + tid*4;
    int v[4]; int local=0;
    #pragma unroll
    for (int k=0;k<4;k++){ int idx=i0+k; v[k]=(idx<n)?cnt[idx]:0; local+=v[k]; }
    sh[tid]=local; __syncthreads();
    for (int d=1; d<256; d<<=1){
        int t = (tid>=d)? sh[tid-d] : 0;
        __syncthreads();
        sh[tid] += t;
        __syncthreads();
    }
    int off = bsum[b] + sh[tid] - local;
    #pragma unroll
    for (int k=0;k<4;k++){
        int idx = i0+k;
        if (idx < n){
            rowptr[idx]=off; wptr[idx]=off; off += v[k];
            if (idx==n-1) rowptr[n]=off;
        }
    }
}
__global__ void k_fill(const int* __restrict__ ei, int* __restrict__ wptr,
                       int* __restrict__ csr, int E, int ET){
    int i = blockIdx.x*256 + threadIdx.x;
    if (i >= ET) return;
    int dst = (i < E) ? ei[E + i] : (i - E);
    int pos = atomicAdd(&wptr[dst], 1);
    csr[pos] = i;   // edge id
}

// ---------------- Layer-1 aggregation via CSR: wave per node, lane = channel
__global__ __launch_bounds__(256) void c_agg1(const int* __restrict__ rowptr,
        const int* __restrict__ csr, const int* __restrict__ ei,
        const float* __restrict__ p, const float* __restrict__ z,
        const float* __restrict__ h1, const float* __restrict__ b1,
        float* __restrict__ out1, int N, int E)
{
    int wid = threadIdx.x>>6, lane = threadIdx.x&63;
    int n = blockIdx.x*4 + wid;
    if (n >= N) return;
    int base = rowptr[n], end = rowptr[n+1];
    float zinv = 1.f / (z[n] + 1e-16f);
    float acc = 0.f;
    for (int k = base; k < end; ++k){
        int eid = csr[k];
        int src = (eid < E) ? ei[eid] : (eid - E);
        acc = fmaf(p[eid], h1[(size_t)src*64 + lane], acc);
    }
    out1[(size_t)n*64 + lane] = fmaxf(acc*zinv + b1[lane], 0.f);
}

// ---------------- Layer-2 aggregation + log_softmax: wave per node, 4 edge-groups x 16 ch
__global__ __launch_bounds__(256) void c_agg2(const int* __restrict__ rowptr,
        const int* __restrict__ csr, const int* __restrict__ ei,
        const float* __restrict__ p, const float* __restrict__ z,
        const float* __restrict__ h2, const float* __restrict__ b2,
        float* __restrict__ out, int N, int E)
{
    int wid = threadIdx.x>>6, lane = threadIdx.x&63;
    int n = blockIdx.x*4 + wid;
    if (n >= N) return;
    int base = rowptr[n], end = rowptr[n+1];
    int c = lane & 15, r = lane >> 4;
    float acc = 0.f;
    for (int k = base + r; k < end; k += 4){
        int eid = csr[k];
        int src = (eid < E) ? ei[eid] : (eid - E);
        acc = fmaf(p[eid], h2[(size_t)src*16 + c], acc);
    }
    acc += __shfl_xor(acc, 16); acc += __shfl_xor(acc, 32);
    float o = acc / (z[n] + 1e-16f) + b2[c];
    float mx = o;
    #pragma unroll
    for (int dd=8; dd>0; dd>>=1) mx = fmaxf(mx, __shfl_xor(mx, dd, 16));
    float ex = expf(o - mx);
    float sum = ex;
    #pragma unroll
    for (int dd=8; dd>0; dd>>=1) sum += __shfl_xor(sum, dd, 16);
    if (r == 0) out[(size_t)n*16 + c] = o - mx - logf(sum);
}

__global__ void n_gemm2(const float* __restrict__ xin, const float* __restrict__ W2,
                        float* __restrict__ h2, int N){
    int idx = blockIdx.x*256 + threadIdx.x;
    if (idx >= N*16) return;
    int n = idx >> 4, c = idx & 15;
    const float* xr = xin + (size_t)n*64;
    float acc = 0.f;
    for (int i = 0; i < 64; ++i) acc = fmaf(xr[i], W2[i*16 + c], acc);
    h2[idx] = acc;
}

extern "C" void kernel_launch(void* const* d_in, const int* in_sizes, int n_in,
                              void* d_out, int out_size, void* d_ws, size_t ws_size,
                              hipStream_t stream)
{
    const float* x      = (const float*)d_in[0];
    const int*   ei     = (const int*)d_in[1];
    const float* W1     = (const float*)d_in[2];
    const float* a_src1 = (const float*)d_in[3];
    const float* a_dst1 = (const float*)d_in[4];
    const float* b1     = (const float*)d_in[5];
    const float* W2     = (const float*)d_in[6];
    const float* a_src2 = (const float*)d_in[7];
    const float* a_dst2 = (const float*)d_in[8];
    const float* b2     = (const float*)d_in[9];
    float* out = (float*)d_out;
    const int N  = in_sizes[0] / 128;
    const int E  = in_sizes[1] / 2;
    const int ET = E + N;   // real edges + self-loops

    char* ptr = (char*)d_ws;
    auto alloc = [&](size_t bytes)->char* {
        char* r = ptr; ptr += (bytes + 255) & ~(size_t)255; return r;
    };
    float*    h1     = (float*)alloc((size_t)N*64*4);
    float*    out1   = (float*)alloc((size_t)N*64*4);
    float*    h2     = (float*)alloc((size_t)N*16*4);
    float*    sbuf   = (float*)alloc((size_t)N*4);
    float*    dbuf   = (float*)alloc((size_t)N*4);
    float*    zbuf   = (float*)alloc((size_t)N*4);
    unsigned* mkey   = (unsigned*)alloc((size_t)N*4);
    float*    pbuf   = (float*)alloc((size_t)ET*4);
    int*      cnt    = (int*)alloc((size_t)N*4);
    int*      rowptr = (int*)alloc((size_t)(N+1)*4);
    int*      wptr   = (int*)alloc((size_t)N*4);
    int*      csr    = (int*)alloc((size_t)ET*4);
    int*      bsum   = (int*)alloc(4096);

    const int gN   = (N + 255)/256;
    const int gN64 = ((size_t)N*64 + 255)/256;
    const int gN16 = ((size_t)N*16 + 255)/256;
    const int gET  = (ET + 255)/256;
    const int nb1  = (N + 1023)/1024;
    const int nbN4 = (N + 3)/4;

    // ---------- CSR build (edge ids, incl. self-loops) ----------
    hipMemsetAsync(cnt, 0, (size_t)N*4, stream);
    k_count<<<gET, 256, 0, stream>>>(ei, cnt, E, ET);
    k_scan1<<<nb1, 256, 0, stream>>>(cnt, bsum, N);
    k_scan2<<<1, 64, 0, stream>>>(bsum, nb1);
    k_scan3<<<nb1, 256, 0, stream>>>(cnt, bsum, rowptr, wptr, N);
    k_fill<<<gET, 256, 0, stream>>>(ei, wptr, csr, E, ET);

    // ---------- layer 1 ----------
    hipMemsetAsync(mkey, 0, (size_t)N*4, stream);
    hipMemsetAsync(zbuf, 0, (size_t)N*4, stream);
    n_gemm1<<<gN64, 256, 0, stream>>>(x, W1, h1, N);
    n_sd   <<<gN,   256, 0, stream>>>(h1, a_src1, a_dst1, sbuf, dbuf, N, 64);
    n_score<<<gET,  256, 0, stream>>>(ei, sbuf, dbuf, pbuf, mkey, E, ET);
    n_z    <<<gET,  256, 0, stream>>>(ei, mkey, pbuf, zbuf, E, ET);
    c_agg1 <<<nbN4, 256, 0, stream>>>(rowptr, csr, ei, pbuf, zbuf, h1, b1, out1, N, E);

    // ---------- layer 2 ----------
    hipMemsetAsync(mkey, 0, (size_t)N*4, stream);
    hipMemsetAsync(zbuf, 0, (size_t)N*4, stream);
    n_gemm2<<<gN16, 256, 0, stream>>>(out1, W2, h2, N);
    n_sd   <<<gN,   256, 0, stream>>>(h2, a_src2, a_dst2, sbuf, dbuf, N, 16);
    n_score<<<gET,  256, 0, stream>>>(ei, sbuf, dbuf, pbuf, mkey, E, ET);
    n_z    <<<gET,  256, 0, stream>>>(ei, mkey, pbuf, zbuf, E, ET);
    c_agg2 <<<nbN4, 256, 0, stream>>>(rowptr, csr, ei, pbuf, zbuf, h2, b2, out, N, E);
}

// Round 5
// 956.094 us; speedup vs baseline: 1.9735x; 1.9735x over previous
//
#include <hip/hip_runtime.h>
#include <math.h>

#define NEG 0.2f

__device__ __forceinline__ float leaky(float x){ return x >= 0.f ? x : NEG*x; }

__device__ __forceinline__ unsigned short f2b(float f){
    unsigned u = __float_as_uint(f);
    unsigned r = u + 0x7fffu + ((u >> 16) & 1u);
    return (unsigned short)(r >> 16);
}
__device__ __forceinline__ float b2f(unsigned short b){
    return __uint_as_float(((unsigned)b) << 16);
}

// ---------------- CSR build (dst -> list of src), incl. self-loops ----------
__global__ void k_count(const int* __restrict__ ei, int* __restrict__ cnt, int E, int ET){
    int i = blockIdx.x*256 + threadIdx.x;
    if (i >= ET) return;
    int dst = (i < E) ? ei[E + i] : (i - E);
    atomicAdd(&cnt[dst], 1);
}
__global__ void k_scan1(const int* __restrict__ cnt, int* __restrict__ bsum, int n){
    __shared__ int sh[256];
    int b = blockIdx.x, tid = threadIdx.x;
    int start = b*1024, s = 0;
    for (int i = tid; i < 1024; i += 256){ int idx = start+i; s += (idx<n)?cnt[idx]:0; }
    sh[tid]=s; __syncthreads();
    for (int d=128; d>0; d>>=1){ if (tid<d) sh[tid]+=sh[tid+d]; __syncthreads(); }
    if (tid==0) bsum[b]=sh[0];
}
__global__ void k_scan2(int* bsum, int nb){
    if (threadIdx.x==0 && blockIdx.x==0){
        int run=0;
        for (int i=0;i<nb;i++){ int v=bsum[i]; bsum[i]=run; run+=v; }
    }
}
__global__ void k_scan3(const int* __restrict__ cnt, const int* __restrict__ bsum,
                        int* __restrict__ rowptr, int* __restrict__ wptr, int n){
    __shared__ int sh[256];
    int b = blockIdx.x, tid = threadIdx.x;
    int i0 = b*1024 + tid*4;
    int v[4]; int local=0;
    #pragma unroll
    for (int k=0;k<4;k++){ int idx=i0+k; v[k]=(idx<n)?cnt[idx]:0; local+=v[k]; }
    sh[tid]=local; __syncthreads();
    for (int d=1; d<256; d<<=1){
        int t = (tid>=d)? sh[tid-d] : 0;
        __syncthreads();
        sh[tid] += t;
        __syncthreads();
    }
    int off = bsum[b] + sh[tid] - local;
    #pragma unroll
    for (int k=0;k<4;k++){
        int idx = i0+k;
        if (idx < n){
            rowptr[idx]=off; wptr[idx]=off; off += v[k];
            if (idx==n-1) rowptr[n]=off;
        }
    }
}
__global__ void k_fill(const int* __restrict__ ei, int* __restrict__ wptr,
                       int* __restrict__ csr, int E, int ET){
    int i = blockIdx.x*256 + threadIdx.x;
    if (i >= ET) return;
    int src = (i < E) ? ei[i]     : (i - E);
    int dst = (i < E) ? ei[E + i] : (i - E);
    int pos = atomicAdd(&wptr[dst], 1);
    csr[pos] = src;
}

// ---------------- g1: h1b(bf16) = x @ W1; s1 = h1·a_src1; d1 = h1·a_dst1 ----
// wave per node, lane = out channel; W1 in barrier-protected LDS; x via
// broadcast float4 loads; s/d via full-wave shfl_xor reduce.
__global__ __launch_bounds__(256) void g1(const float* __restrict__ x,
        const float* __restrict__ W1, const float* __restrict__ a_src,
        const float* __restrict__ a_dst, unsigned short* __restrict__ h1b,
        float* __restrict__ s1, float* __restrict__ d1, int N)
{
    __shared__ float w[128*64];
    const int tid = threadIdx.x, wid = tid >> 6, lane = tid & 63;
    for (int k = tid; k < 128*64/4; k += 256)
        ((float4*)w)[k] = ((const float4*)W1)[k];
    __syncthreads();
    const float as = a_src[lane], ad = a_dst[lane];
    for (int n = blockIdx.x*4 + wid; n < N; n += gridDim.x*4) {
        const float4* xr = (const float4*)(x + (size_t)n*128);
        float acc = 0.f;
        #pragma unroll
        for (int i4 = 0; i4 < 32; ++i4) {
            float4 v = xr[i4];
            acc = fmaf(v.x, w[(i4*4+0)*64 + lane], acc);
            acc = fmaf(v.y, w[(i4*4+1)*64 + lane], acc);
            acc = fmaf(v.z, w[(i4*4+2)*64 + lane], acc);
            acc = fmaf(v.w, w[(i4*4+3)*64 + lane], acc);
        }
        h1b[(size_t)n*64 + lane] = f2b(acc);
        float sv = acc*as, dv = acc*ad;
        #pragma unroll
        for (int dd = 32; dd > 0; dd >>= 1){ sv += __shfl_xor(sv, dd); dv += __shfl_xor(dv, dd); }
        if (lane == 0) { s1[n] = sv; d1[n] = dv; }
    }
}

// ---------------- a1: fused softmax+aggregate layer 1 (no-max softmax) ------
// wave per dst node, lane = channel; e recomputed in-register per edge
// (csr/s1 reads are wave-broadcast; only the h1b row read is per-lane).
__global__ __launch_bounds__(256) void a1(const int* __restrict__ rowptr,
        const int* __restrict__ csr, const unsigned short* __restrict__ h1b,
        const float* __restrict__ s1, const float* __restrict__ d1,
        const float* __restrict__ b1, float* __restrict__ out1, int N)
{
    int wid = threadIdx.x>>6, lane = threadIdx.x&63;
    int n = blockIdx.x*4 + wid;
    if (n >= N) return;
    int base = rowptr[n], end = rowptr[n+1];
    float dn = d1[n];
    float z = 0.f, acc = 0.f;
    for (int k = base; k < end; ++k){
        int src = csr[k];
        float pv = expf(leaky(s1[src] + dn));
        z += pv;
        acc = fmaf(pv, b2f(h1b[(size_t)src*64 + lane]), acc);
    }
    out1[(size_t)n*64 + lane] = fmaxf(acc/(z + 1e-16f) + b1[lane], 0.f);
}

// ---------------- g2: h2b(bf16) = out1 @ W2; s2; d2 ------------------------
// 16 lanes per node (4 nodes/wave); W2 in LDS; width-16 shfl_xor reduce.
__global__ __launch_bounds__(256) void g2(const float* __restrict__ xin,
        const float* __restrict__ W2, const float* __restrict__ a_src,
        const float* __restrict__ a_dst, unsigned short* __restrict__ h2b,
        float* __restrict__ s2, float* __restrict__ d2, int N)
{
    __shared__ float w[64*16];
    const int tid = threadIdx.x;
    for (int k = tid; k < 64*16/4; k += 256)
        ((float4*)w)[k] = ((const float4*)W2)[k];
    __syncthreads();
    int idx = blockIdx.x*256 + tid;
    int n = idx >> 4, c = idx & 15;
    if (n >= N) return;
    const float as = a_src[c], ad = a_dst[c];
    const float4* xr = (const float4*)(xin + (size_t)n*64);
    float acc = 0.f;
    #pragma unroll
    for (int i4 = 0; i4 < 16; ++i4) {
        float4 v = xr[i4];
        acc = fmaf(v.x, w[(i4*4+0)*16 + c], acc);
        acc = fmaf(v.y, w[(i4*4+1)*16 + c], acc);
        acc = fmaf(v.z, w[(i4*4+2)*16 + c], acc);
        acc = fmaf(v.w, w[(i4*4+3)*16 + c], acc);
    }
    h2b[(size_t)n*16 + c] = f2b(acc);
    float sv = acc*as, dv = acc*ad;
    #pragma unroll
    for (int dd = 8; dd > 0; dd >>= 1){ sv += __shfl_xor(sv, dd, 16); dv += __shfl_xor(dv, dd, 16); }
    if (c == 0) { s2[n] = sv; d2[n] = dv; }
}

// ---------------- a2: fused softmax+aggregate layer 2 + log_softmax --------
// wave per node: 4 edge-groups x 16 channels.
__global__ __launch_bounds__(256) void a2(const int* __restrict__ rowptr,
        const int* __restrict__ csr, const unsigned short* __restrict__ h2b,
        const float* __restrict__ s2, const float* __restrict__ d2,
        const float* __restrict__ b2, float* __restrict__ out, int N)
{
    int wid = threadIdx.x>>6, lane = threadIdx.x&63;
    int n = blockIdx.x*4 + wid;
    if (n >= N) return;
    int base = rowptr[n], end = rowptr[n+1];
    int c = lane & 15, r = lane >> 4;
    float dn = d2[n];
    float z = 0.f, acc = 0.f;
    for (int k = base + r; k < end; k += 4){
        int src = csr[k];
        float pv = expf(leaky(s2[src] + dn));
        z += pv;
        acc = fmaf(pv, b2f(h2b[(size_t)src*16 + c]), acc);
    }
    acc += __shfl_xor(acc, 16); acc += __shfl_xor(acc, 32);
    z   += __shfl_xor(z, 16);   z   += __shfl_xor(z, 32);
    float o = acc/(z + 1e-16f) + b2[c];
    float mx = o;
    #pragma unroll
    for (int dd=8; dd>0; dd>>=1) mx = fmaxf(mx, __shfl_xor(mx, dd, 16));
    float ex = expf(o - mx);
    float sum = ex;
    #pragma unroll
    for (int dd=8; dd>0; dd>>=1) sum += __shfl_xor(sum, dd, 16);
    if (r == 0) out[(size_t)n*16 + c] = o - mx - logf(sum);
}

extern "C" void kernel_launch(void* const* d_in, const int* in_sizes, int n_in,
                              void* d_out, int out_size, void* d_ws, size_t ws_size,
                              hipStream_t stream)
{
    const float* x      = (const float*)d_in[0];
    const int*   ei     = (const int*)d_in[1];
    const float* W1     = (const float*)d_in[2];
    const float* a_src1 = (const float*)d_in[3];
    const float* a_dst1 = (const float*)d_in[4];
    const float* b1     = (const float*)d_in[5];
    const float* W2     = (const float*)d_in[6];
    const float* a_src2 = (const float*)d_in[7];
    const float* a_dst2 = (const float*)d_in[8];
    const float* b2     = (const float*)d_in[9];
    float* out = (float*)d_out;
    const int N  = in_sizes[0] / 128;
    const int E  = in_sizes[1] / 2;
    const int ET = E + N;

    char* ptr = (char*)d_ws;
    auto alloc = [&](size_t bytes)->char* {
        char* r = ptr; ptr += (bytes + 255) & ~(size_t)255; return r;
    };
    unsigned short* h1b   = (unsigned short*)alloc((size_t)N*64*2);
    unsigned short* h2b   = (unsigned short*)alloc((size_t)N*16*2);
    float*          out1  = (float*)alloc((size_t)N*64*4);
    float*          s1    = (float*)alloc((size_t)N*4);
    float*          d1    = (float*)alloc((size_t)N*4);
    float*          s2    = (float*)alloc((size_t)N*4);
    float*          d2v   = (float*)alloc((size_t)N*4);
    int*            cnt   = (int*)alloc((size_t)N*4);
    int*            rowptr= (int*)alloc((size_t)(N+1)*4);
    int*            wptr  = (int*)alloc((size_t)N*4);
    int*            csr   = (int*)alloc((size_t)ET*4);
    int*            bsum  = (int*)alloc(4096);

    const int gET  = (ET + 255)/256;
    const int nb1  = (N + 1023)/1024;
    const int nbN4 = (N + 3)/4;
    const int gN16 = ((size_t)N*16 + 255)/256;

    // CSR build
    hipMemsetAsync(cnt, 0, (size_t)N*4, stream);
    k_count<<<gET, 256, 0, stream>>>(ei, cnt, E, ET);
    k_scan1<<<nb1, 256, 0, stream>>>(cnt, bsum, N);
    k_scan2<<<1, 64, 0, stream>>>(bsum, nb1);
    k_scan3<<<nb1, 256, 0, stream>>>(cnt, bsum, rowptr, wptr, N);
    k_fill<<<gET, 256, 0, stream>>>(ei, wptr, csr, E, ET);

    // layer 1
    g1<<<2048, 256, 0, stream>>>(x, W1, a_src1, a_dst1, h1b, s1, d1, N);
    a1<<<nbN4, 256, 0, stream>>>(rowptr, csr, h1b, s1, d1, b1, out1, N);

    // layer 2
    g2<<<gN16, 256, 0, stream>>>(out1, W2, a_src2, a_dst2, h2b, s2, d2v, N);
    a2<<<nbN4, 256, 0, stream>>>(rowptr, csr, h2b, s2, d2v, b2, out, N);
}

// Round 6
// 676.082 us; speedup vs baseline: 2.7909x; 1.4142x over previous
//
#include <hip/hip_runtime.h>
#include <math.h>

#define NEG 0.2f

__device__ __forceinline__ float leaky(float x){ return x >= 0.f ? x : NEG*x; }

__device__ __forceinline__ unsigned short f2b(float f){
    unsigned u = __float_as_uint(f);
    unsigned r = u + 0x7fffu + ((u >> 16) & 1u);
    return (unsigned short)(r >> 16);
}
__device__ __forceinline__ float b2f(unsigned short b){
    return __uint_as_float(((unsigned)b) << 16);
}

// ---------------- CSR build (dst -> slots), posbuf[i] = slot of edge i ------
__global__ void k_count(const int* __restrict__ ei, int* __restrict__ cnt, int E, int ET){
    int i = blockIdx.x*256 + threadIdx.x;
    if (i >= ET) return;
    int dst = (i < E) ? ei[E + i] : (i - E);
    atomicAdd(&cnt[dst], 1);
}
__global__ void k_scan1(const int* __restrict__ cnt, int* __restrict__ bsum, int n){
    __shared__ int sh[256];
    int b = blockIdx.x, tid = threadIdx.x;
    int start = b*1024, s = 0;
    for (int i = tid; i < 1024; i += 256){ int idx = start+i; s += (idx<n)?cnt[idx]:0; }
    sh[tid]=s; __syncthreads();
    for (int d=128; d>0; d>>=1){ if (tid<d) sh[tid]+=sh[tid+d]; __syncthreads(); }
    if (tid==0) bsum[b]=sh[0];
}
__global__ void k_scan2(int* bsum, int nb){
    if (threadIdx.x==0 && blockIdx.x==0){
        int run=0;
        for (int i=0;i<nb;i++){ int v=bsum[i]; bsum[i]=run; run+=v; }
    }
}
__global__ void k_scan3(const int* __restrict__ cnt, const int* __restrict__ bsum,
                        int* __restrict__ rowptr, int* __restrict__ wptr, int n){
    __shared__ int sh[256];
    int b = blockIdx.x, tid = threadIdx.x;
    int i0 = b*1024 + tid*4;
    int v[4]; int local=0;
    #pragma unroll
    for (int k=0;k<4;k++){ int idx=i0+k; v[k]=(idx<n)?cnt[idx]:0; local+=v[k]; }
    sh[tid]=local; __syncthreads();
    for (int d=1; d<256; d<<=1){
        int t = (tid>=d)? sh[tid-d] : 0;
        __syncthreads();
        sh[tid] += t;
        __syncthreads();
    }
    int off = bsum[b] + sh[tid] - local;
    #pragma unroll
    for (int k=0;k<4;k++){
        int idx = i0+k;
        if (idx < n){
            rowptr[idx]=off; wptr[idx]=off; off += v[k];
            if (idx==n-1) rowptr[n]=off;
        }
    }
}
__global__ void k_fill(const int* __restrict__ ei, int* __restrict__ wptr,
                       int* __restrict__ posbuf, int E, int ET){
    int i = blockIdx.x*256 + threadIdx.x;
    if (i >= ET) return;
    int dst = (i < E) ? ei[E + i] : (i - E);
    posbuf[i] = atomicAdd(&wptr[dst], 1);
}

// ---------------- score: edge-parallel p = exp(leaky(s[src]+d[dst])),
// packed {src, p_bits} scattered into CSR slot order.
__global__ void k_score(const int* __restrict__ ei, const int* __restrict__ posbuf,
                        const float* __restrict__ s, const float* __restrict__ d,
                        int2* __restrict__ csrp, int E, int ET){
    int i = blockIdx.x*256 + threadIdx.x;
    if (i >= ET) return;
    int src = (i < E) ? ei[i]     : (i - E);
    int dst = (i < E) ? ei[E + i] : (i - E);
    float pv = expf(leaky(s[src] + d[dst]));
    csrp[posbuf[i]] = make_int2(src, __float_as_int(pv));
}

// ---------------- g1: h1b(bf16) = x @ W1; s1; d1 ---------------------------
__global__ __launch_bounds__(256) void g1(const float* __restrict__ x,
        const float* __restrict__ W1, const float* __restrict__ a_src,
        const float* __restrict__ a_dst, unsigned short* __restrict__ h1b,
        float* __restrict__ s1, float* __restrict__ d1, int N)
{
    __shared__ float w[128*64];
    const int tid = threadIdx.x, wid = tid >> 6, lane = tid & 63;
    for (int k = tid; k < 128*64/4; k += 256)
        ((float4*)w)[k] = ((const float4*)W1)[k];
    __syncthreads();
    const float as = a_src[lane], ad = a_dst[lane];
    for (int n = blockIdx.x*4 + wid; n < N; n += gridDim.x*4) {
        const float4* xr = (const float4*)(x + (size_t)n*128);
        float acc = 0.f;
        #pragma unroll
        for (int i4 = 0; i4 < 32; ++i4) {
            float4 v = xr[i4];
            acc = fmaf(v.x, w[(i4*4+0)*64 + lane], acc);
            acc = fmaf(v.y, w[(i4*4+1)*64 + lane], acc);
            acc = fmaf(v.z, w[(i4*4+2)*64 + lane], acc);
            acc = fmaf(v.w, w[(i4*4+3)*64 + lane], acc);
        }
        h1b[(size_t)n*64 + lane] = f2b(acc);
        float sv = acc*as, dv = acc*ad;
        #pragma unroll
        for (int dd = 32; dd > 0; dd >>= 1){ sv += __shfl_xor(sv, dd); dv += __shfl_xor(dv, dd); }
        if (lane == 0) { s1[n] = sv; d1[n] = dv; }
    }
}

// ---------------- a1: aggregate layer 1 (p precomputed) --------------------
// wave per dst node, lane = channel. Inner loop: one 8B broadcast load +
// one gathered 2B/lane row load + 2 fma.
__global__ __launch_bounds__(256) void a1(const int* __restrict__ rowptr,
        const int2* __restrict__ csrp, const unsigned short* __restrict__ h1b,
        const float* __restrict__ b1, float* __restrict__ out1, int N)
{
    int wid = threadIdx.x>>6, lane = threadIdx.x&63;
    int n = blockIdx.x*4 + wid;
    if (n >= N) return;
    int base = rowptr[n], end = rowptr[n+1];
    float z = 0.f, acc = 0.f;
    #pragma unroll 4
    for (int k = base; k < end; ++k){
        int2 cp = csrp[k];
        float pv = __int_as_float(cp.y);
        z += pv;
        acc = fmaf(pv, b2f(h1b[(size_t)cp.x*64 + lane]), acc);
    }
    out1[(size_t)n*64 + lane] = fmaxf(acc/(z + 1e-16f) + b1[lane], 0.f);
}

// ---------------- g2: h2b(bf16) = out1 @ W2; s2; d2 ------------------------
__global__ __launch_bounds__(256) void g2(const float* __restrict__ xin,
        const float* __restrict__ W2, const float* __restrict__ a_src,
        const float* __restrict__ a_dst, unsigned short* __restrict__ h2b,
        float* __restrict__ s2, float* __restrict__ d2, int N)
{
    __shared__ float w[64*16];
    const int tid = threadIdx.x;
    for (int k = tid; k < 64*16/4; k += 256)
        ((float4*)w)[k] = ((const float4*)W2)[k];
    __syncthreads();
    int idx = blockIdx.x*256 + tid;
    int n = idx >> 4, c = idx & 15;
    if (n >= N) return;
    const float as = a_src[c], ad = a_dst[c];
    const float4* xr = (const float4*)(xin + (size_t)n*64);
    float acc = 0.f;
    #pragma unroll
    for (int i4 = 0; i4 < 16; ++i4) {
        float4 v = xr[i4];
        acc = fmaf(v.x, w[(i4*4+0)*16 + c], acc);
        acc = fmaf(v.y, w[(i4*4+1)*16 + c], acc);
        acc = fmaf(v.z, w[(i4*4+2)*16 + c], acc);
        acc = fmaf(v.w, w[(i4*4+3)*16 + c], acc);
    }
    h2b[(size_t)n*16 + c] = f2b(acc);
    float sv = acc*as, dv = acc*ad;
    #pragma unroll
    for (int dd = 8; dd > 0; dd >>= 1){ sv += __shfl_xor(sv, dd, 16); dv += __shfl_xor(dv, dd, 16); }
    if (c == 0) { s2[n] = sv; d2[n] = dv; }
}

// ---------------- a2: aggregate layer 2 + log_softmax ----------------------
// wave per node: 4 edge-groups x 16 channels.
__global__ __launch_bounds__(256) void a2(const int* __restrict__ rowptr,
        const int2* __restrict__ csrp, const unsigned short* __restrict__ h2b,
        const float* __restrict__ b2, float* __restrict__ out, int N)
{
    int wid = threadIdx.x>>6, lane = threadIdx.x&63;
    int n = blockIdx.x*4 + wid;
    if (n >= N) return;
    int base = rowptr[n], end = rowptr[n+1];
    int c = lane & 15, r = lane >> 4;
    float z = 0.f, acc = 0.f;
    #pragma unroll 2
    for (int k = base + r; k < end; k += 4){
        int2 cp = csrp[k];
        float pv = __int_as_float(cp.y);
        z += pv;
        acc = fmaf(pv, b2f(h2b[(size_t)cp.x*16 + c]), acc);
    }
    acc += __shfl_xor(acc, 16); acc += __shfl_xor(acc, 32);
    z   += __shfl_xor(z, 16);   z   += __shfl_xor(z, 32);
    float o = acc/(z + 1e-16f) + b2[c];
    float mx = o;
    #pragma unroll
    for (int dd=8; dd>0; dd>>=1) mx = fmaxf(mx, __shfl_xor(mx, dd, 16));
    float ex = expf(o - mx);
    float sum = ex;
    #pragma unroll
    for (int dd=8; dd>0; dd>>=1) sum += __shfl_xor(sum, dd, 16);
    if (r == 0) out[(size_t)n*16 + c] = o - mx - logf(sum);
}

extern "C" void kernel_launch(void* const* d_in, const int* in_sizes, int n_in,
                              void* d_out, int out_size, void* d_ws, size_t ws_size,
                              hipStream_t stream)
{
    const float* x      = (const float*)d_in[0];
    const int*   ei     = (const int*)d_in[1];
    const float* W1     = (const float*)d_in[2];
    const float* a_src1 = (const float*)d_in[3];
    const float* a_dst1 = (const float*)d_in[4];
    const float* b1     = (const float*)d_in[5];
    const float* W2     = (const float*)d_in[6];
    const float* a_src2 = (const float*)d_in[7];
    const float* a_dst2 = (const float*)d_in[8];
    const float* b2     = (const float*)d_in[9];
    float* out = (float*)d_out;
    const int N  = in_sizes[0] / 128;
    const int E  = in_sizes[1] / 2;
    const int ET = E + N;

    char* ptr = (char*)d_ws;
    auto alloc = [&](size_t bytes)->char* {
        char* r = ptr; ptr += (bytes + 255) & ~(size_t)255; return r;
    };
    unsigned short* h1b    = (unsigned short*)alloc((size_t)N*64*2);
    unsigned short* h2b    = (unsigned short*)alloc((size_t)N*16*2);
    float*          out1   = (float*)alloc((size_t)N*64*4);
    float*          s1     = (float*)alloc((size_t)N*4);
    float*          d1     = (float*)alloc((size_t)N*4);
    float*          s2     = (float*)alloc((size_t)N*4);
    float*          d2v    = (float*)alloc((size_t)N*4);
    int*            cnt    = (int*)alloc((size_t)N*4);
    int*            rowptr = (int*)alloc((size_t)(N+1)*4);
    int*            wptr   = (int*)alloc((size_t)N*4);
    int*            posbuf = (int*)alloc((size_t)ET*4);
    int2*           csrp   = (int2*)alloc((size_t)ET*8);
    int*            bsum   = (int*)alloc(4096);

    const int gET  = (ET + 255)/256;
    const int nb1  = (N + 1023)/1024;
    const int nbN4 = (N + 3)/4;
    const int gN16 = ((size_t)N*16 + 255)/256;

    // CSR build (slot assignment only)
    hipMemsetAsync(cnt, 0, (size_t)N*4, stream);
    k_count<<<gET, 256, 0, stream>>>(ei, cnt, E, ET);
    k_scan1<<<nb1, 256, 0, stream>>>(cnt, bsum, N);
    k_scan2<<<1, 64, 0, stream>>>(bsum, nb1);
    k_scan3<<<nb1, 256, 0, stream>>>(cnt, bsum, rowptr, wptr, N);
    k_fill<<<gET, 256, 0, stream>>>(ei, wptr, posbuf, E, ET);

    // layer 1
    g1<<<2048, 256, 0, stream>>>(x, W1, a_src1, a_dst1, h1b, s1, d1, N);
    k_score<<<gET, 256, 0, stream>>>(ei, posbuf, s1, d1, csrp, E, ET);
    a1<<<nbN4, 256, 0, stream>>>(rowptr, csrp, h1b, b1, out1, N);

    // layer 2
    g2<<<gN16, 256, 0, stream>>>(out1, W2, a_src2, a_dst2, h2b, s2, d2v, N);
    k_score<<<gET, 256, 0, stream>>>(ei, posbuf, s2, d2v, csrp, E, ET);
    a2<<<nbN4, 256, 0, stream>>>(rowptr, csrp, h2b, b2, out, N);
}

// Round 7
// 663.114 us; speedup vs baseline: 2.8454x; 1.0196x over previous
//
#include <hip/hip_runtime.h>
#include <math.h>

#define NEG 0.2f

__device__ __forceinline__ float leaky(float x){ return x >= 0.f ? x : NEG*x; }

__device__ __forceinline__ unsigned short f2b(float f){
    unsigned u = __float_as_uint(f);
    unsigned r = u + 0x7fffu + ((u >> 16) & 1u);
    return (unsigned short)(r >> 16);
}
__device__ __forceinline__ float b2f(unsigned short b){
    return __uint_as_float(((unsigned)b) << 16);
}

// ---------------- CSR build: ONE atomic pass assigns per-dst rank ----------
__global__ void k_rank(const int* __restrict__ ei, int* __restrict__ cnt,
                       int* __restrict__ rank, int E, int ET){
    int i = blockIdx.x*256 + threadIdx.x;
    if (i >= ET) return;
    int dst = (i < E) ? ei[E + i] : (i - E);
    rank[i] = atomicAdd(&cnt[dst], 1);
}
__global__ void k_scan1(const int* __restrict__ cnt, int* __restrict__ bsum, int n){
    __shared__ int sh[256];
    int b = blockIdx.x, tid = threadIdx.x;
    int start = b*1024, s = 0;
    for (int i = tid; i < 1024; i += 256){ int idx = start+i; s += (idx<n)?cnt[idx]:0; }
    sh[tid]=s; __syncthreads();
    for (int d=128; d>0; d>>=1){ if (tid<d) sh[tid]+=sh[tid+d]; __syncthreads(); }
    if (tid==0) bsum[b]=sh[0];
}
__global__ void k_scan2(int* bsum, int nb){
    if (threadIdx.x==0 && blockIdx.x==0){
        int run=0;
        for (int i=0;i<nb;i++){ int v=bsum[i]; bsum[i]=run; run+=v; }
    }
}
__global__ void k_scan3(const int* __restrict__ cnt, const int* __restrict__ bsum,
                        int* __restrict__ rowptr, int n){
    __shared__ int sh[256];
    int b = blockIdx.x, tid = threadIdx.x;
    int i0 = b*1024 + tid*4;
    int v[4]; int local=0;
    #pragma unroll
    for (int k=0;k<4;k++){ int idx=i0+k; v[k]=(idx<n)?cnt[idx]:0; local+=v[k]; }
    sh[tid]=local; __syncthreads();
    for (int d=1; d<256; d<<=1){
        int t = (tid>=d)? sh[tid-d] : 0;
        __syncthreads();
        sh[tid] += t;
        __syncthreads();
    }
    int off = bsum[b] + sh[tid] - local;
    #pragma unroll
    for (int k=0;k<4;k++){
        int idx = i0+k;
        if (idx < n){
            rowptr[idx]=off; off += v[k];
            if (idx==n-1) rowptr[n]=off;
        }
    }
}

// ---------------- score: edge-parallel p = exp(leaky(s[src]+d[dst])),
// packed {src, p_bits} scattered into CSR slot rowptr[dst]+rank[i].
__global__ void k_score(const int* __restrict__ ei, const int* __restrict__ rank,
                        const int* __restrict__ rowptr,
                        const float* __restrict__ s, const float* __restrict__ d,
                        int2* __restrict__ csrp, int E, int ET){
    int i = blockIdx.x*256 + threadIdx.x;
    if (i >= ET) return;
    int src = (i < E) ? ei[i]     : (i - E);
    int dst = (i < E) ? ei[E + i] : (i - E);
    float pv = expf(leaky(s[src] + d[dst]));
    csrp[rowptr[dst] + rank[i]] = make_int2(src, __float_as_int(pv));
}

// ---------------- g1: h1b(bf16) = x @ W1; s1; d1 ---------------------------
// wave per row, lane = out channel. W1 column held in REGISTERS (static
// fully-unrolled indexing, no LDS, no barriers). 4 rotating accumulators.
__global__ __launch_bounds__(256, 3) void g1(const float* __restrict__ x,
        const float* __restrict__ W1, const float* __restrict__ a_src,
        const float* __restrict__ a_dst, unsigned short* __restrict__ h1b,
        float* __restrict__ s1, float* __restrict__ d1, int N)
{
    const int tid = threadIdx.x, wid = tid >> 6, lane = tid & 63;
    float wv[128];
    #pragma unroll
    for (int i = 0; i < 128; ++i) wv[i] = W1[i*64 + lane];
    const float as = a_src[lane], ad = a_dst[lane];
    for (int n = blockIdx.x*4 + wid; n < N; n += gridDim.x*4) {
        const float4* xr = (const float4*)(x + (size_t)n*128);
        float c0=0.f, c1=0.f, c2=0.f, c3=0.f;
        #pragma unroll
        for (int i4 = 0; i4 < 32; i4 += 4) {
            float4 v0 = xr[i4+0], v1 = xr[i4+1], v2 = xr[i4+2], v3 = xr[i4+3];
            c0 = fmaf(v0.x, wv[4*i4+ 0], c0); c0 = fmaf(v0.y, wv[4*i4+ 1], c0);
            c0 = fmaf(v0.z, wv[4*i4+ 2], c0); c0 = fmaf(v0.w, wv[4*i4+ 3], c0);
            c1 = fmaf(v1.x, wv[4*i4+ 4], c1); c1 = fmaf(v1.y, wv[4*i4+ 5], c1);
            c1 = fmaf(v1.z, wv[4*i4+ 6], c1); c1 = fmaf(v1.w, wv[4*i4+ 7], c1);
            c2 = fmaf(v2.x, wv[4*i4+ 8], c2); c2 = fmaf(v2.y, wv[4*i4+ 9], c2);
            c2 = fmaf(v2.z, wv[4*i4+10], c2); c2 = fmaf(v2.w, wv[4*i4+11], c2);
            c3 = fmaf(v3.x, wv[4*i4+12], c3); c3 = fmaf(v3.y, wv[4*i4+13], c3);
            c3 = fmaf(v3.z, wv[4*i4+14], c3); c3 = fmaf(v3.w, wv[4*i4+15], c3);
        }
        float acc = (c0 + c1) + (c2 + c3);
        h1b[(size_t)n*64 + lane] = f2b(acc);
        float sv = acc*as, dv = acc*ad;
        #pragma unroll
        for (int dd = 32; dd > 0; dd >>= 1){ sv += __shfl_xor(sv, dd); dv += __shfl_xor(dv, dd); }
        if (lane == 0) { s1[n] = sv; d1[n] = dv; }
    }
}

// ---------------- a1: aggregate layer 1 (p precomputed) --------------------
__global__ __launch_bounds__(256) void a1(const int* __restrict__ rowptr,
        const int2* __restrict__ csrp, const unsigned short* __restrict__ h1b,
        const float* __restrict__ b1, float* __restrict__ out1, int N)
{
    int wid = threadIdx.x>>6, lane = threadIdx.x&63;
    int n = blockIdx.x*4 + wid;
    if (n >= N) return;
    int base = rowptr[n], end = rowptr[n+1];
    float z = 0.f, acc = 0.f;
    #pragma unroll 4
    for (int k = base; k < end; ++k){
        int2 cp = csrp[k];
        float pv = __int_as_float(cp.y);
        z += pv;
        acc = fmaf(pv, b2f(h1b[(size_t)cp.x*64 + lane]), acc);
    }
    out1[(size_t)n*64 + lane] = fmaxf(acc/(z + 1e-16f) + b1[lane], 0.f);
}

// ---------------- g2: h2b(bf16) = out1 @ W2; s2; d2 ------------------------
__global__ __launch_bounds__(256) void g2(const float* __restrict__ xin,
        const float* __restrict__ W2, const float* __restrict__ a_src,
        const float* __restrict__ a_dst, unsigned short* __restrict__ h2b,
        float* __restrict__ s2, float* __restrict__ d2, int N)
{
    __shared__ float w[64*16];
    const int tid = threadIdx.x;
    for (int k = tid; k < 64*16/4; k += 256)
        ((float4*)w)[k] = ((const float4*)W2)[k];
    __syncthreads();
    int idx = blockIdx.x*256 + tid;
    int n = idx >> 4, c = idx & 15;
    if (n >= N) return;
    const float as = a_src[c], ad = a_dst[c];
    const float4* xr = (const float4*)(xin + (size_t)n*64);
    float acc = 0.f;
    #pragma unroll
    for (int i4 = 0; i4 < 16; ++i4) {
        float4 v = xr[i4];
        acc = fmaf(v.x, w[(i4*4+0)*16 + c], acc);
        acc = fmaf(v.y, w[(i4*4+1)*16 + c], acc);
        acc = fmaf(v.z, w[(i4*4+2)*16 + c], acc);
        acc = fmaf(v.w, w[(i4*4+3)*16 + c], acc);
    }
    h2b[(size_t)n*16 + c] = f2b(acc);
    float sv = acc*as, dv = acc*ad;
    #pragma unroll
    for (int dd = 8; dd > 0; dd >>= 1){ sv += __shfl_xor(sv, dd, 16); dv += __shfl_xor(dv, dd, 16); }
    if (c == 0) { s2[n] = sv; d2[n] = dv; }
}

// ---------------- a2: aggregate layer 2 + log_softmax ----------------------
__global__ __launch_bounds__(256) void a2(const int* __restrict__ rowptr,
        const int2* __restrict__ csrp, const unsigned short* __restrict__ h2b,
        const float* __restrict__ b2, float* __restrict__ out, int N)
{
    int wid = threadIdx.x>>6, lane = threadIdx.x&63;
    int n = blockIdx.x*4 + wid;
    if (n >= N) return;
    int base = rowptr[n], end = rowptr[n+1];
    int c = lane & 15, r = lane >> 4;
    float z = 0.f, acc = 0.f;
    #pragma unroll 2
    for (int k = base + r; k < end; k += 4){
        int2 cp = csrp[k];
        float pv = __int_as_float(cp.y);
        z += pv;
        acc = fmaf(pv, b2f(h2b[(size_t)cp.x*16 + c]), acc);
    }
    acc += __shfl_xor(acc, 16); acc += __shfl_xor(acc, 32);
    z   += __shfl_xor(z, 16);   z   += __shfl_xor(z, 32);
    float o = acc/(z + 1e-16f) + b2[c];
    float mx = o;
    #pragma unroll
    for (int dd=8; dd>0; dd>>=1) mx = fmaxf(mx, __shfl_xor(mx, dd, 16));
    float ex = expf(o - mx);
    float sum = ex;
    #pragma unroll
    for (int dd=8; dd>0; dd>>=1) sum += __shfl_xor(sum, dd, 16);
    if (r == 0) out[(size_t)n*16 + c] = o - mx - logf(sum);
}

extern "C" void kernel_launch(void* const* d_in, const int* in_sizes, int n_in,
                              void* d_out, int out_size, void* d_ws, size_t ws_size,
                              hipStream_t stream)
{
    const float* x      = (const float*)d_in[0];
    const int*   ei     = (const int*)d_in[1];
    const float* W1     = (const float*)d_in[2];
    const float* a_src1 = (const float*)d_in[3];
    const float* a_dst1 = (const float*)d_in[4];
    const float* b1     = (const float*)d_in[5];
    const float* W2     = (const float*)d_in[6];
    const float* a_src2 = (const float*)d_in[7];
    const float* a_dst2 = (const float*)d_in[8];
    const float* b2     = (const float*)d_in[9];
    float* out = (float*)d_out;
    const int N  = in_sizes[0] / 128;
    const int E  = in_sizes[1] / 2;
    const int ET = E + N;

    char* ptr = (char*)d_ws;
    auto alloc = [&](size_t bytes)->char* {
        char* r = ptr; ptr += (bytes + 255) & ~(size_t)255; return r;
    };
    unsigned short* h1b    = (unsigned short*)alloc((size_t)N*64*2);
    unsigned short* h2b    = (unsigned short*)alloc((size_t)N*16*2);
    float*          out1   = (float*)alloc((size_t)N*64*4);
    float*          s1     = (float*)alloc((size_t)N*4);
    float*          d1     = (float*)alloc((size_t)N*4);
    float*          s2     = (float*)alloc((size_t)N*4);
    float*          d2v    = (float*)alloc((size_t)N*4);
    int*            cnt    = (int*)alloc((size_t)N*4);
    int*            rowptr = (int*)alloc((size_t)(N+1)*4);
    int*            rank   = (int*)alloc((size_t)ET*4);
    int2*           csrp   = (int2*)alloc((size_t)ET*8);
    int*            bsum   = (int*)alloc(4096);

    const int gET  = (ET + 255)/256;
    const int nb1  = (N + 1023)/1024;
    const int nbN4 = (N + 3)/4;
    const int gN16 = ((size_t)N*16 + 255)/256;

    // CSR slot assignment: one atomic pass + scan
    hipMemsetAsync(cnt, 0, (size_t)N*4, stream);
    k_rank<<<gET, 256, 0, stream>>>(ei, cnt, rank, E, ET);
    k_scan1<<<nb1, 256, 0, stream>>>(cnt, bsum, N);
    k_scan2<<<1, 64, 0, stream>>>(bsum, nb1);
    k_scan3<<<nb1, 256, 0, stream>>>(cnt, bsum, rowptr, N);

    // layer 1
    g1<<<2048, 256, 0, stream>>>(x, W1, a_src1, a_dst1, h1b, s1, d1, N);
    k_score<<<gET, 256, 0, stream>>>(ei, rank, rowptr, s1, d1, csrp, E, ET);
    a1<<<nbN4, 256, 0, stream>>>(rowptr, csrp, h1b, b1, out1, N);

    // layer 2
    g2<<<gN16, 256, 0, stream>>>(out1, W2, a_src2, a_dst2, h2b, s2, d2v, N);
    k_score<<<gET, 256, 0, stream>>>(ei, rank, rowptr, s2, d2v, csrp, E, ET);
    a2<<<nbN4, 256, 0, stream>>>(rowptr, csrp, h2b, b2, out, N);
}

// Round 8
// 491.202 us; speedup vs baseline: 3.8413x; 1.3500x over previous
//
#include <hip/hip_runtime.h>
#include <math.h>

#define NEG 0.2f

__device__ __forceinline__ float leaky(float x){ return x >= 0.f ? x : NEG*x; }

__device__ __forceinline__ unsigned short f2b(float f){
    unsigned u = __float_as_uint(f);
    unsigned r = u + 0x7fffu + ((u >> 16) & 1u);
    return (unsigned short)(r >> 16);
}
__device__ __forceinline__ float b2f(unsigned short b){
    return __uint_as_float(((unsigned)b) << 16);
}

// ---------------- CSR build: ONE atomic pass assigns per-dst rank ----------
__global__ void k_rank(const int* __restrict__ ei, int* __restrict__ cnt,
                       int* __restrict__ rank, int E, int ET){
    int i = blockIdx.x*256 + threadIdx.x;
    if (i >= ET) return;
    int dst = (i < E) ? ei[E + i] : (i - E);
    rank[i] = atomicAdd(&cnt[dst], 1);
}
__global__ void k_scan1(const int* __restrict__ cnt, int* __restrict__ bsum, int n){
    __shared__ int sh[256];
    int b = blockIdx.x, tid = threadIdx.x;
    int start = b*1024, s = 0;
    for (int i = tid; i < 1024; i += 256){ int idx = start+i; s += (idx<n)?cnt[idx]:0; }
    sh[tid]=s; __syncthreads();
    for (int d=128; d>0; d>>=1){ if (tid<d) sh[tid]+=sh[tid+d]; __syncthreads(); }
    if (tid==0) bsum[b]=sh[0];
}
__global__ void k_scan2(int* bsum, int nb){
    if (threadIdx.x==0 && blockIdx.x==0){
        int run=0;
        for (int i=0;i<nb;i++){ int v=bsum[i]; bsum[i]=run; run+=v; }
    }
}
__global__ void k_scan3(const int* __restrict__ cnt, const int* __restrict__ bsum,
                        int* __restrict__ rowptr, int n){
    __shared__ int sh[256];
    int b = blockIdx.x, tid = threadIdx.x;
    int i0 = b*1024 + tid*4;
    int v[4]; int local=0;
    #pragma unroll
    for (int k=0;k<4;k++){ int idx=i0+k; v[k]=(idx<n)?cnt[idx]:0; local+=v[k]; }
    sh[tid]=local; __syncthreads();
    for (int d=1; d<256; d<<=1){
        int t = (tid>=d)? sh[tid-d] : 0;
        __syncthreads();
        sh[tid] += t;
        __syncthreads();
    }
    int off = bsum[b] + sh[tid] - local;
    #pragma unroll
    for (int k=0;k<4;k++){
        int idx = i0+k;
        if (idx < n){
            rowptr[idx]=off; off += v[k];
            if (idx==n-1) rowptr[n]=off;
        }
    }
}

// ---------------- score: edge-parallel p = exp(leaky(s[src]+d[dst])),
// packed {src, p_bits} scattered into CSR slot rowptr[dst]+rank[i].
__global__ void k_score(const int* __restrict__ ei, const int* __restrict__ rank,
                        const int* __restrict__ rowptr,
                        const float* __restrict__ s, const float* __restrict__ d,
                        int2* __restrict__ csrp, int E, int ET){
    int i = blockIdx.x*256 + threadIdx.x;
    if (i >= ET) return;
    int src = (i < E) ? ei[i]     : (i - E);
    int dst = (i < E) ? ei[E + i] : (i - E);
    float pv = expf(leaky(s[src] + d[dst]));
    csrp[rowptr[dst] + rank[i]] = make_int2(src, __float_as_int(pv));
}

// ---------------- g1: outer-product register-tile GEMM -------------------
// block = 256 threads = 16x16; tile = 64 rows x 64 cols, K=128 staged once.
// thread (ty,tx): 4 rows x 4 cols accumulator; 8 ds_read_b128 + 64 FMA per
// k4 step. s1/d1 via width-16 shfl reduce in epilogue.
__global__ __launch_bounds__(256) void g1(const float* __restrict__ x,
        const float* __restrict__ W1, const float* __restrict__ a_src,
        const float* __restrict__ a_dst, unsigned short* __restrict__ h1b,
        float* __restrict__ s1, float* __restrict__ d1, int N)
{
    __shared__ float xsh[64][132];   // padded: stride 132 floats
    __shared__ float wsh[128][64];
    const int tid = threadIdx.x;
    const int rowbase = blockIdx.x * 64;
    // stage W1 (2048 float4 granules)
    #pragma unroll
    for (int i = 0; i < 8; ++i){
        int g = tid + i*256;
        ((float4*)&wsh[0][0])[g] = ((const float4*)W1)[g];
    }
    // stage x tile (64 rows x 32 granules)
    #pragma unroll
    for (int i = 0; i < 8; ++i){
        int g = tid + i*256;
        int r = g >> 5, c4 = g & 31;
        int grow = rowbase + r;
        float4 v = make_float4(0.f,0.f,0.f,0.f);
        if (grow < N) v = ((const float4*)(x + (size_t)grow*128))[c4];
        *(float4*)&xsh[r][c4*4] = v;
    }
    __syncthreads();
    const int tx = tid & 15, ty = tid >> 4;
    float acc[4][4];
    #pragma unroll
    for (int j=0;j<4;++j){
        #pragma unroll
        for (int c=0;c<4;++c) acc[j][c]=0.f;
    }
    #pragma unroll 4
    for (int k4 = 0; k4 < 32; ++k4){
        float4 xv[4], wv[4];
        #pragma unroll
        for (int j=0;j<4;++j) xv[j] = *(const float4*)&xsh[ty*4+j][k4*4];
        #pragma unroll
        for (int i=0;i<4;++i) wv[i] = *(const float4*)&wsh[k4*4+i][tx*4];
        #pragma unroll
        for (int j=0;j<4;++j){
            float x0=xv[j].x, x1=xv[j].y, x2=xv[j].z, x3=xv[j].w;
            acc[j][0]=fmaf(x0,wv[0].x,acc[j][0]); acc[j][1]=fmaf(x0,wv[0].y,acc[j][1]);
            acc[j][2]=fmaf(x0,wv[0].z,acc[j][2]); acc[j][3]=fmaf(x0,wv[0].w,acc[j][3]);
            acc[j][0]=fmaf(x1,wv[1].x,acc[j][0]); acc[j][1]=fmaf(x1,wv[1].y,acc[j][1]);
            acc[j][2]=fmaf(x1,wv[1].z,acc[j][2]); acc[j][3]=fmaf(x1,wv[1].w,acc[j][3]);
            acc[j][0]=fmaf(x2,wv[2].x,acc[j][0]); acc[j][1]=fmaf(x2,wv[2].y,acc[j][1]);
            acc[j][2]=fmaf(x2,wv[2].z,acc[j][2]); acc[j][3]=fmaf(x2,wv[2].w,acc[j][3]);
            acc[j][0]=fmaf(x3,wv[3].x,acc[j][0]); acc[j][1]=fmaf(x3,wv[3].y,acc[j][1]);
            acc[j][2]=fmaf(x3,wv[3].z,acc[j][2]); acc[j][3]=fmaf(x3,wv[3].w,acc[j][3]);
        }
    }
    // epilogue: h1b (bf16 x4 packed) + s1/d1 partial dot + width-16 reduce
    const float4 asv = *(const float4*)&a_src[tx*4];
    const float4 adv = *(const float4*)&a_dst[tx*4];
    #pragma unroll
    for (int j=0;j<4;++j){
        int r = rowbase + ty*4 + j;
        float sv = acc[j][0]*asv.x + acc[j][1]*asv.y + acc[j][2]*asv.z + acc[j][3]*asv.w;
        float dv = acc[j][0]*adv.x + acc[j][1]*adv.y + acc[j][2]*adv.z + acc[j][3]*adv.w;
        #pragma unroll
        for (int dd=8; dd>0; dd>>=1){ sv += __shfl_xor(sv, dd, 16); dv += __shfl_xor(dv, dd, 16); }
        if (r < N){
            uint2 pk;
            pk.x = (unsigned)f2b(acc[j][0]) | ((unsigned)f2b(acc[j][1]) << 16);
            pk.y = (unsigned)f2b(acc[j][2]) | ((unsigned)f2b(acc[j][3]) << 16);
            *(uint2*)&h1b[(size_t)r*64 + tx*4] = pk;
            if (tx == 0){ s1[r] = sv; d1[r] = dv; }
        }
    }
}

// ---------------- a1: aggregate layer 1 (p precomputed) --------------------
__global__ __launch_bounds__(256) void a1(const int* __restrict__ rowptr,
        const int2* __restrict__ csrp, const unsigned short* __restrict__ h1b,
        const float* __restrict__ b1, float* __restrict__ out1, int N)
{
    int wid = threadIdx.x>>6, lane = threadIdx.x&63;
    int n = blockIdx.x*4 + wid;
    if (n >= N) return;
    int base = rowptr[n], end = rowptr[n+1];
    float z = 0.f, acc = 0.f;
    #pragma unroll 4
    for (int k = base; k < end; ++k){
        int2 cp = csrp[k];
        float pv = __int_as_float(cp.y);
        z += pv;
        acc = fmaf(pv, b2f(h1b[(size_t)cp.x*64 + lane]), acc);
    }
    out1[(size_t)n*64 + lane] = fmaxf(acc/(z + 1e-16f) + b1[lane], 0.f);
}

// ---------------- g2: h2b(bf16) = out1 @ W2; s2; d2 ------------------------
__global__ __launch_bounds__(256) void g2(const float* __restrict__ xin,
        const float* __restrict__ W2, const float* __restrict__ a_src,
        const float* __restrict__ a_dst, unsigned short* __restrict__ h2b,
        float* __restrict__ s2, float* __restrict__ d2, int N)
{
    __shared__ float w[64*16];
    const int tid = threadIdx.x;
    for (int k = tid; k < 64*16/4; k += 256)
        ((float4*)w)[k] = ((const float4*)W2)[k];
    __syncthreads();
    int idx = blockIdx.x*256 + tid;
    int n = idx >> 4, c = idx & 15;
    if (n >= N) return;
    const float as = a_src[c], ad = a_dst[c];
    const float4* xr = (const float4*)(xin + (size_t)n*64);
    float acc = 0.f;
    #pragma unroll
    for (int i4 = 0; i4 < 16; ++i4) {
        float4 v = xr[i4];
        acc = fmaf(v.x, w[(i4*4+0)*16 + c], acc);
        acc = fmaf(v.y, w[(i4*4+1)*16 + c], acc);
        acc = fmaf(v.z, w[(i4*4+2)*16 + c], acc);
        acc = fmaf(v.w, w[(i4*4+3)*16 + c], acc);
    }
    h2b[(size_t)n*16 + c] = f2b(acc);
    float sv = acc*as, dv = acc*ad;
    #pragma unroll
    for (int dd = 8; dd > 0; dd >>= 1){ sv += __shfl_xor(sv, dd, 16); dv += __shfl_xor(dv, dd, 16); }
    if (c == 0) { s2[n] = sv; d2[n] = dv; }
}

// ---------------- a2: aggregate layer 2 + log_softmax ----------------------
__global__ __launch_bounds__(256) void a2(const int* __restrict__ rowptr,
        const int2* __restrict__ csrp, const unsigned short* __restrict__ h2b,
        const float* __restrict__ b2, float* __restrict__ out, int N)
{
    int wid = threadIdx.x>>6, lane = threadIdx.x&63;
    int n = blockIdx.x*4 + wid;
    if (n >= N) return;
    int base = rowptr[n], end = rowptr[n+1];
    int c = lane & 15, r = lane >> 4;
    float z = 0.f, acc = 0.f;
    #pragma unroll 2
    for (int k = base + r; k < end; k += 4){
        int2 cp = csrp[k];
        float pv = __int_as_float(cp.y);
        z += pv;
        acc = fmaf(pv, b2f(h2b[(size_t)cp.x*16 + c]), acc);
    }
    acc += __shfl_xor(acc, 16); acc += __shfl_xor(acc, 32);
    z   += __shfl_xor(z, 16);   z   += __shfl_xor(z, 32);
    float o = acc/(z + 1e-16f) + b2[c];
    float mx = o;
    #pragma unroll
    for (int dd=8; dd>0; dd>>=1) mx = fmaxf(mx, __shfl_xor(mx, dd, 16));
    float ex = expf(o - mx);
    float sum = ex;
    #pragma unroll
    for (int dd=8; dd>0; dd>>=1) sum += __shfl_xor(sum, dd, 16);
    if (r == 0) out[(size_t)n*16 + c] = o - mx - logf(sum);
}

extern "C" void kernel_launch(void* const* d_in, const int* in_sizes, int n_in,
                              void* d_out, int out_size, void* d_ws, size_t ws_size,
                              hipStream_t stream)
{
    const float* x      = (const float*)d_in[0];
    const int*   ei     = (const int*)d_in[1];
    const float* W1     = (const float*)d_in[2];
    const float* a_src1 = (const float*)d_in[3];
    const float* a_dst1 = (const float*)d_in[4];
    const float* b1     = (const float*)d_in[5];
    const float* W2     = (const float*)d_in[6];
    const float* a_src2 = (const float*)d_in[7];
    const float* a_dst2 = (const float*)d_in[8];
    const float* b2     = (const float*)d_in[9];
    float* out = (float*)d_out;
    const int N  = in_sizes[0] / 128;
    const int E  = in_sizes[1] / 2;
    const int ET = E + N;

    char* ptr = (char*)d_ws;
    auto alloc = [&](size_t bytes)->char* {
        char* r = ptr; ptr += (bytes + 255) & ~(size_t)255; return r;
    };
    unsigned short* h1b    = (unsigned short*)alloc((size_t)N*64*2);
    unsigned short* h2b    = (unsigned short*)alloc((size_t)N*16*2);
    float*          out1   = (float*)alloc((size_t)N*64*4);
    float*          s1     = (float*)alloc((size_t)N*4);
    float*          d1     = (float*)alloc((size_t)N*4);
    float*          s2     = (float*)alloc((size_t)N*4);
    float*          d2v    = (float*)alloc((size_t)N*4);
    int*            cnt    = (int*)alloc((size_t)N*4);
    int*            rowptr = (int*)alloc((size_t)(N+1)*4);
    int*            rank   = (int*)alloc((size_t)ET*4);
    int2*           csrp   = (int2*)alloc((size_t)ET*8);
    int*            bsum   = (int*)alloc(4096);

    const int gET  = (ET + 255)/256;
    const int nb1  = (N + 1023)/1024;
    const int nbN4 = (N + 3)/4;
    const int gN16 = ((size_t)N*16 + 255)/256;
    const int gG1  = (N + 63)/64;

    // CSR slot assignment: one atomic pass + scan
    hipMemsetAsync(cnt, 0, (size_t)N*4, stream);
    k_rank<<<gET, 256, 0, stream>>>(ei, cnt, rank, E, ET);
    k_scan1<<<nb1, 256, 0, stream>>>(cnt, bsum, N);
    k_scan2<<<1, 64, 0, stream>>>(bsum, nb1);
    k_scan3<<<nb1, 256, 0, stream>>>(cnt, bsum, rowptr, N);

    // layer 1
    g1<<<gG1, 256, 0, stream>>>(x, W1, a_src1, a_dst1, h1b, s1, d1, N);
    k_score<<<gET, 256, 0, stream>>>(ei, rank, rowptr, s1, d1, csrp, E, ET);
    a1<<<nbN4, 256, 0, stream>>>(rowptr, csrp, h1b, b1, out1, N);

    // layer 2
    g2<<<gN16, 256, 0, stream>>>(out1, W2, a_src2, a_dst2, h2b, s2, d2v, N);
    k_score<<<gET, 256, 0, stream>>>(ei, rank, rowptr, s2, d2v, csrp, E, ET);
    a2<<<nbN4, 256, 0, stream>>>(rowptr, csrp, h2b, b2, out, N);
}

// Round 9
// 445.523 us; speedup vs baseline: 4.2351x; 1.1025x over previous
//
#include <hip/hip_runtime.h>
#include <math.h>

#define NEG 0.2f

__device__ __forceinline__ float leaky(float x){ return x >= 0.f ? x : NEG*x; }

__device__ __forceinline__ unsigned short f2b(float f){
    unsigned u = __float_as_uint(f);
    unsigned r = u + 0x7fffu + ((u >> 16) & 1u);
    return (unsigned short)(r >> 16);
}

// ---------------- CSR build: ONE atomic pass assigns per-dst rank ----------
// cnt padded to one counter per 64B line (stride 16) to cut line contention.
__global__ void k_rank(const int* __restrict__ ei, int* __restrict__ cnt,
                       int* __restrict__ rank, int E, int ET){
    int i = blockIdx.x*256 + threadIdx.x;
    if (i >= ET) return;
    int dst = (i < E) ? ei[E + i] : (i - E);
    rank[i] = atomicAdd(&cnt[dst << 4], 1);
}
__global__ void k_scan1(const int* __restrict__ cnt, int* __restrict__ bsum, int n){
    __shared__ int sh[256];
    int b = blockIdx.x, tid = threadIdx.x;
    int start = b*1024, s = 0;
    for (int i = tid; i < 1024; i += 256){ int idx = start+i; s += (idx<n)?cnt[idx<<4]:0; }
    sh[tid]=s; __syncthreads();
    for (int d=128; d>0; d>>=1){ if (tid<d) sh[tid]+=sh[tid+d]; __syncthreads(); }
    if (tid==0) bsum[b]=sh[0];
}
__global__ void k_scan2(int* bsum, int nb){
    if (threadIdx.x==0 && blockIdx.x==0){
        int run=0;
        for (int i=0;i<nb;i++){ int v=bsum[i]; bsum[i]=run; run+=v; }
    }
}
__global__ void k_scan3(const int* __restrict__ cnt, const int* __restrict__ bsum,
                        int* __restrict__ rowptr, int n){
    __shared__ int sh[256];
    int b = blockIdx.x, tid = threadIdx.x;
    int i0 = b*1024 + tid*4;
    int v[4]; int local=0;
    #pragma unroll
    for (int k=0;k<4;k++){ int idx=i0+k; v[k]=(idx<n)?cnt[idx<<4]:0; local+=v[k]; }
    sh[tid]=local; __syncthreads();
    for (int d=1; d<256; d<<=1){
        int t = (tid>=d)? sh[tid-d] : 0;
        __syncthreads();
        sh[tid] += t;
        __syncthreads();
    }
    int off = bsum[b] + sh[tid] - local;
    #pragma unroll
    for (int k=0;k<4;k++){
        int idx = i0+k;
        if (idx < n){
            rowptr[idx]=off; off += v[k];
            if (idx==n-1) rowptr[n]=off;
        }
    }
}

// ---------------- score: edge-parallel p = exp(leaky(s[src]+d[dst])),
// packed {src, p_bits} scattered into CSR slot rowptr[dst]+rank[i].
__global__ void k_score(const int* __restrict__ ei, const int* __restrict__ rank,
                        const int* __restrict__ rowptr,
                        const float* __restrict__ s, const float* __restrict__ d,
                        int2* __restrict__ csrp, int E, int ET){
    int i = blockIdx.x*256 + threadIdx.x;
    if (i >= ET) return;
    int src = (i < E) ? ei[i]     : (i - E);
    int dst = (i < E) ? ei[E + i] : (i - E);
    float pv = expf(leaky(s[src] + d[dst]));
    csrp[rowptr[dst] + rank[i]] = make_int2(src, __float_as_int(pv));
}

// ---------------- g1: outer-product register-tile GEMM -------------------
__global__ __launch_bounds__(256) void g1(const float* __restrict__ x,
        const float* __restrict__ W1, const float* __restrict__ a_src,
        const float* __restrict__ a_dst, unsigned short* __restrict__ h1b,
        float* __restrict__ s1, float* __restrict__ d1, int N)
{
    __shared__ float xsh[64][132];
    __shared__ float wsh[128][64];
    const int tid = threadIdx.x;
    const int rowbase = blockIdx.x * 64;
    #pragma unroll
    for (int i = 0; i < 8; ++i){
        int g = tid + i*256;
        ((float4*)&wsh[0][0])[g] = ((const float4*)W1)[g];
    }
    #pragma unroll
    for (int i = 0; i < 8; ++i){
        int g = tid + i*256;
        int r = g >> 5, c4 = g & 31;
        int grow = rowbase + r;
        float4 v = make_float4(0.f,0.f,0.f,0.f);
        if (grow < N) v = ((const float4*)(x + (size_t)grow*128))[c4];
        *(float4*)&xsh[r][c4*4] = v;
    }
    __syncthreads();
    const int tx = tid & 15, ty = tid >> 4;
    float acc[4][4];
    #pragma unroll
    for (int j=0;j<4;++j){
        #pragma unroll
        for (int c=0;c<4;++c) acc[j][c]=0.f;
    }
    #pragma unroll 4
    for (int k4 = 0; k4 < 32; ++k4){
        float4 xv[4], wv[4];
        #pragma unroll
        for (int j=0;j<4;++j) xv[j] = *(const float4*)&xsh[ty*4+j][k4*4];
        #pragma unroll
        for (int i=0;i<4;++i) wv[i] = *(const float4*)&wsh[k4*4+i][tx*4];
        #pragma unroll
        for (int j=0;j<4;++j){
            float x0=xv[j].x, x1=xv[j].y, x2=xv[j].z, x3=xv[j].w;
            acc[j][0]=fmaf(x0,wv[0].x,acc[j][0]); acc[j][1]=fmaf(x0,wv[0].y,acc[j][1]);
            acc[j][2]=fmaf(x0,wv[0].z,acc[j][2]); acc[j][3]=fmaf(x0,wv[0].w,acc[j][3]);
            acc[j][0]=fmaf(x1,wv[1].x,acc[j][0]); acc[j][1]=fmaf(x1,wv[1].y,acc[j][1]);
            acc[j][2]=fmaf(x1,wv[1].z,acc[j][2]); acc[j][3]=fmaf(x1,wv[1].w,acc[j][3]);
            acc[j][0]=fmaf(x2,wv[2].x,acc[j][0]); acc[j][1]=fmaf(x2,wv[2].y,acc[j][1]);
            acc[j][2]=fmaf(x2,wv[2].z,acc[j][2]); acc[j][3]=fmaf(x2,wv[2].w,acc[j][3]);
            acc[j][0]=fmaf(x3,wv[3].x,acc[j][0]); acc[j][1]=fmaf(x3,wv[3].y,acc[j][1]);
            acc[j][2]=fmaf(x3,wv[3].z,acc[j][2]); acc[j][3]=fmaf(x3,wv[3].w,acc[j][3]);
        }
    }
    const float4 asv = *(const float4*)&a_src[tx*4];
    const float4 adv = *(const float4*)&a_dst[tx*4];
    #pragma unroll
    for (int j=0;j<4;++j){
        int r = rowbase + ty*4 + j;
        float sv = acc[j][0]*asv.x + acc[j][1]*asv.y + acc[j][2]*asv.z + acc[j][3]*asv.w;
        float dv = acc[j][0]*adv.x + acc[j][1]*adv.y + acc[j][2]*adv.z + acc[j][3]*adv.w;
        #pragma unroll
        for (int dd=8; dd>0; dd>>=1){ sv += __shfl_xor(sv, dd, 16); dv += __shfl_xor(dv, dd, 16); }
        if (r < N){
            uint2 pk;
            pk.x = (unsigned)f2b(acc[j][0]) | ((unsigned)f2b(acc[j][1]) << 16);
            pk.y = (unsigned)f2b(acc[j][2]) | ((unsigned)f2b(acc[j][3]) << 16);
            *(uint2*)&h1b[(size_t)r*64 + tx*4] = pk;
            if (tx == 0){ s1[r] = sv; d1[r] = dv; }
        }
    }
}

// ---------------- a1: aggregate layer 1, 8 edges x 8 channel-groups -------
// lane = es*8+cg: edge-slot es handles edge base+i*8+es; lane loads ushort8
// (16B) = channels cg*8..cg*8+7 -> 1KB per gather instruction (8 rows).
__global__ __launch_bounds__(256) void a1(const int* __restrict__ rowptr,
        const int2* __restrict__ csrp, const unsigned short* __restrict__ h1b,
        const float* __restrict__ b1, float* __restrict__ out1, int N)
{
    int wid = threadIdx.x>>6, lane = threadIdx.x&63;
    int n = blockIdx.x*4 + wid;
    if (n >= N) return;
    int base = rowptr[n], end = rowptr[n+1];
    int es = lane >> 3, cg = lane & 7;
    float a0=0.f,a1v=0.f,a2v=0.f,a3=0.f,a4=0.f,a5=0.f,a6=0.f,a7=0.f;
    float z = 0.f;
    for (int k = base + es; k < end; k += 8){
        int2 cp = csrp[k];
        float pv = __int_as_float(cp.y);
        z += pv;
        uint4 hv = *(const uint4*)(h1b + (size_t)cp.x*64 + cg*8);
        a0 = fmaf(pv, __uint_as_float(hv.x << 16),          a0);
        a1v= fmaf(pv, __uint_as_float(hv.x & 0xffff0000u),  a1v);
        a2v= fmaf(pv, __uint_as_float(hv.y << 16),          a2v);
        a3 = fmaf(pv, __uint_as_float(hv.y & 0xffff0000u),  a3);
        a4 = fmaf(pv, __uint_as_float(hv.z << 16),          a4);
        a5 = fmaf(pv, __uint_as_float(hv.z & 0xffff0000u),  a5);
        a6 = fmaf(pv, __uint_as_float(hv.w << 16),          a6);
        a7 = fmaf(pv, __uint_as_float(hv.w & 0xffff0000u),  a7);
    }
    #pragma unroll
    for (int m = 8; m <= 32; m <<= 1){
        a0 += __shfl_xor(a0, m); a1v += __shfl_xor(a1v, m);
        a2v += __shfl_xor(a2v, m); a3 += __shfl_xor(a3, m);
        a4 += __shfl_xor(a4, m); a5 += __shfl_xor(a5, m);
        a6 += __shfl_xor(a6, m); a7 += __shfl_xor(a7, m);
        z  += __shfl_xor(z, m);
    }
    if (es == 0){
        float zi = 1.f/(z + 1e-16f);
        const float4 b0 = *(const float4*)(b1 + cg*8);
        const float4 b4 = *(const float4*)(b1 + cg*8 + 4);
        float4 o0 = make_float4(fmaxf(a0*zi + b0.x, 0.f), fmaxf(a1v*zi + b0.y, 0.f),
                                fmaxf(a2v*zi + b0.z, 0.f), fmaxf(a3*zi + b0.w, 0.f));
        float4 o4 = make_float4(fmaxf(a4*zi + b4.x, 0.f), fmaxf(a5*zi + b4.y, 0.f),
                                fmaxf(a6*zi + b4.z, 0.f), fmaxf(a7*zi + b4.w, 0.f));
        float* op = out1 + (size_t)n*64 + cg*8;
        *(float4*)op = o0;
        *(float4*)(op+4) = o4;
    }
}

// ---------------- g2: h2b(bf16) = out1 @ W2; s2; d2 ------------------------
__global__ __launch_bounds__(256) void g2(const float* __restrict__ xin,
        const float* __restrict__ W2, const float* __restrict__ a_src,
        const float* __restrict__ a_dst, unsigned short* __restrict__ h2b,
        float* __restrict__ s2, float* __restrict__ d2, int N)
{
    __shared__ float w[64*16];
    const int tid = threadIdx.x;
    for (int k = tid; k < 64*16/4; k += 256)
        ((float4*)w)[k] = ((const float4*)W2)[k];
    __syncthreads();
    int idx = blockIdx.x*256 + tid;
    int n = idx >> 4, c = idx & 15;
    if (n >= N) return;
    const float as = a_src[c], ad = a_dst[c];
    const float4* xr = (const float4*)(xin + (size_t)n*64);
    float acc = 0.f;
    #pragma unroll
    for (int i4 = 0; i4 < 16; ++i4) {
        float4 v = xr[i4];
        acc = fmaf(v.x, w[(i4*4+0)*16 + c], acc);
        acc = fmaf(v.y, w[(i4*4+1)*16 + c], acc);
        acc = fmaf(v.z, w[(i4*4+2)*16 + c], acc);
        acc = fmaf(v.w, w[(i4*4+3)*16 + c], acc);
    }
    h2b[(size_t)n*16 + c] = f2b(acc);
    float sv = acc*as, dv = acc*ad;
    #pragma unroll
    for (int dd = 8; dd > 0; dd >>= 1){ sv += __shfl_xor(sv, dd, 16); dv += __shfl_xor(dv, dd, 16); }
    if (c == 0) { s2[n] = sv; d2[n] = dv; }
}

// ---------------- a2: aggregate layer 2 + log_softmax ----------------------
// lane = es*8+cg: 8 edge-slots; lane loads ushort2 = channels 2cg,2cg+1.
__global__ __launch_bounds__(256) void a2(const int* __restrict__ rowptr,
        const int2* __restrict__ csrp, const unsigned short* __restrict__ h2b,
        const float* __restrict__ b2, float* __restrict__ out, int N)
{
    int wid = threadIdx.x>>6, lane = threadIdx.x&63;
    int n = blockIdx.x*4 + wid;
    if (n >= N) return;
    int base = rowptr[n], end = rowptr[n+1];
    int es = lane >> 3, cg = lane & 7;
    float a0=0.f, a1v=0.f, z=0.f;
    for (int k = base + es; k < end; k += 8){
        int2 cp = csrp[k];
        float pv = __int_as_float(cp.y);
        z += pv;
        unsigned hv = *(const unsigned*)(h2b + (size_t)cp.x*16 + cg*2);
        a0 = fmaf(pv, __uint_as_float(hv << 16),         a0);
        a1v= fmaf(pv, __uint_as_float(hv & 0xffff0000u), a1v);
    }
    #pragma unroll
    for (int m = 8; m <= 32; m <<= 1){
        a0 += __shfl_xor(a0, m); a1v += __shfl_xor(a1v, m); z += __shfl_xor(z, m);
    }
    float zi = 1.f/(z + 1e-16f);
    float2 bv = *(const float2*)(b2 + cg*2);
    float o0 = a0*zi + bv.x;
    float o1 = a1v*zi + bv.y;
    float mx = fmaxf(o0, o1);
    #pragma unroll
    for (int m = 1; m <= 4; m <<= 1) mx = fmaxf(mx, __shfl_xor(mx, m));
    float sum = expf(o0 - mx) + expf(o1 - mx);
    #pragma unroll
    for (int m = 1; m <= 4; m <<= 1) sum += __shfl_xor(sum, m);
    if (es == 0){
        float ls = logf(sum);
        *(float2*)(out + (size_t)n*16 + cg*2) = make_float2(o0 - mx - ls, o1 - mx - ls);
    }
}

extern "C" void kernel_launch(void* const* d_in, const int* in_sizes, int n_in,
                              void* d_out, int out_size, void* d_ws, size_t ws_size,
                              hipStream_t stream)
{
    const float* x      = (const float*)d_in[0];
    const int*   ei     = (const int*)d_in[1];
    const float* W1     = (const float*)d_in[2];
    const float* a_src1 = (const float*)d_in[3];
    const float* a_dst1 = (const float*)d_in[4];
    const float* b1     = (const float*)d_in[5];
    const float* W2     = (const float*)d_in[6];
    const float* a_src2 = (const float*)d_in[7];
    const float* a_dst2 = (const float*)d_in[8];
    const float* b2     = (const float*)d_in[9];
    float* out = (float*)d_out;
    const int N  = in_sizes[0] / 128;
    const int E  = in_sizes[1] / 2;
    const int ET = E + N;

    char* ptr = (char*)d_ws;
    auto alloc = [&](size_t bytes)->char* {
        char* r = ptr; ptr += (bytes + 255) & ~(size_t)255; return r;
    };
    unsigned short* h1b    = (unsigned short*)alloc((size_t)N*64*2);
    unsigned short* h2b    = (unsigned short*)alloc((size_t)N*16*2);
    float*          out1   = (float*)alloc((size_t)N*64*4);
    float*          s1     = (float*)alloc((size_t)N*4);
    float*          d1     = (float*)alloc((size_t)N*4);
    float*          s2     = (float*)alloc((size_t)N*4);
    float*          d2v    = (float*)alloc((size_t)N*4);
    int*            cnt    = (int*)alloc((size_t)N*16*4);   // padded: 1 counter / 64B
    int*            rowptr = (int*)alloc((size_t)(N+1)*4);
    int*            rank   = (int*)alloc((size_t)ET*4);
    int2*           csrp   = (int2*)alloc((size_t)ET*8);
    int*            bsum   = (int*)alloc(4096);

    const int gET  = (ET + 255)/256;
    const int nb1  = (N + 1023)/1024;
    const int nbN4 = (N + 3)/4;
    const int gN16 = ((size_t)N*16 + 255)/256;
    const int gG1  = (N + 63)/64;

    // CSR slot assignment: one atomic pass + scan
    hipMemsetAsync(cnt, 0, (size_t)N*16*4, stream);
    k_rank<<<gET, 256, 0, stream>>>(ei, cnt, rank, E, ET);
    k_scan1<<<nb1, 256, 0, stream>>>(cnt, bsum, N);
    k_scan2<<<1, 64, 0, stream>>>(bsum, nb1);
    k_scan3<<<nb1, 256, 0, stream>>>(cnt, bsum, rowptr, N);

    // layer 1
    g1<<<gG1, 256, 0, stream>>>(x, W1, a_src1, a_dst1, h1b, s1, d1, N);
    k_score<<<gET, 256, 0, stream>>>(ei, rank, rowptr, s1, d1, csrp, E, ET);
    a1<<<nbN4, 256, 0, stream>>>(rowptr, csrp, h1b, b1, out1, N);

    // layer 2
    g2<<<gN16, 256, 0, stream>>>(out1, W2, a_src2, a_dst2, h2b, s2, d2v, N);
    k_score<<<gET, 256, 0, stream>>>(ei, rank, rowptr, s2, d2v, csrp, E, ET);
    a2<<<nbN4, 256, 0, stream>>>(rowptr, csrp, h2b, b2, out, N);
}